// Round 11
// baseline (236.807 us; speedup 1.0000x reference)
//
#include <hip/hip_runtime.h>

// Problem geometry (fixed by the reference):
//   x: (16, 480, 64, 64) fp32;  fields: pattern {1,1,2,2,4,4,8,8} x16 groups
//   N_FIELDS=128, C_TOTAL=480, plane = 64*64 = 4096 floats (16 KB, contiguous)
#define NB      16
#define NC      480
#define NF      128
#define HW      4096
#define PLANES  (NB * NC)      // 7680
#define EPS     1e-6f

typedef float vfloat4 __attribute__((ext_vector_type(4)));   // native vec for NT store

// ---------------------------------------------------------------------------
// Kernel 1: per-(batch,channel) sum of squares. One WAVE per plane:
// lane l reads float4 l, l+64, ..., l+960 (16 loads, fully coalesced, deep
// MLP), shuffle-reduces within the wave, lane 0 stores. No LDS, no barriers.
// 4 waves (4 planes) per 256-thread block -> 1920 blocks.
// ---------------------------------------------------------------------------
__global__ __launch_bounds__(256) void k_sumsq(const float* __restrict__ x,
                                               float* __restrict__ sq) {
    const int w    = threadIdx.x >> 6;
    const int lane = threadIdx.x & 63;
    const int plane = blockIdx.x * 4 + w;

    const vfloat4* xp = reinterpret_cast<const vfloat4*>(x) + (size_t)plane * (HW / 4);

    float s = 0.f;
#pragma unroll
    for (int i = 0; i < 16; ++i) {
        vfloat4 v = xp[lane + 64 * i];
        s = fmaf(v.x, v.x, s);
        s = fmaf(v.y, v.y, s);
        s = fmaf(v.z, v.z, s);
        s = fmaf(v.w, v.w, s);
    }
#pragma unroll
    for (int off = 32; off > 0; off >>= 1) s += __shfl_down(s, off, 64);
    if (lane == 0) sq[plane] = s;
}

// ---------------------------------------------------------------------------
// Kernel 2 (fused): block prologue recomputes per-batch field stats from sq
// (1.9 KB, L2-hot; redundant across blocks but ~free), then each WAVE applies
//   out = x * a[f] + beta[f]   (a = 1 + gamma*nx)
// to one plane with 16 float4 loads + 16 nontemporal float4 stores per lane.
// NT stores keep x resident in L3 for this kernel's own reads.
// 4 planes per block (480 % 4 == 0 -> block never straddles batches).
// ---------------------------------------------------------------------------
__global__ __launch_bounds__(256) void k_apply(const float* __restrict__ x,
                                               const float* __restrict__ sq,
                                               const float* __restrict__ gamma,
                                               const float* __restrict__ beta,
                                               float* __restrict__ out) {
    const int pbase = blockIdx.x * 4;
    const int b = pbase / NC;            // batch (uniform per block)
    const int t = threadIdx.x;

    __shared__ float af[NF];
    __shared__ float bf[NF];
    __shared__ float wsum[4];

    // --- per-field gx (threads 0..127; one field each) ---
    float gx = 0.f;
    if (t < NF) {
        const int offs[8] = {0, 1, 2, 4, 6, 10, 14, 22};
        const int szs[8]  = {1, 1, 2, 2, 4, 4, 8, 8};
        const int k = t & 7, g = t >> 3;
        const int start = b * NC + g * 30 + offs[k];
        float s = 0.f;
        for (int i = 0; i < szs[k]; ++i) s += sq[start + i];
        gx = sqrtf(s);
    }
    // mean over the 128 fields (waves 2,3 contribute zeros)
    float m = gx;
#pragma unroll
    for (int off = 32; off > 0; off >>= 1) m += __shfl_down(m, off, 64);
    if ((t & 63) == 0) wsum[t >> 6] = m;
    __syncthreads();
    const float mean = (wsum[0] + wsum[1]) * (1.0f / (float)NF);
    if (t < NF) {
        const float nx = gx / (mean + EPS);
        af[t] = 1.0f + gamma[t] * nx;
        bf[t] = beta[t];
    }
    __syncthreads();

    // --- one wave per plane ---
    const int w    = t >> 6;
    const int lane = t & 63;
    const int plane = pbase + w;
    const int c = plane - b * NC;          // channel 0..479 (wave-uniform)
    const int g = c / 30;
    const int r = c - g * 30;
    // slot within group from cumulative sizes {0,1,2,4,6,10,14,22,30}
    const int k = (r >= 22) ? 7 : (r >= 14) ? 6 : (r >= 10) ? 5 :
                  (r >= 6)  ? 4 : (r >= 4)  ? 3 : (r >= 2)  ? 2 : r;
    const float a  = af[g * 8 + k];
    const float be = bf[g * 8 + k];

    const vfloat4* xp = reinterpret_cast<const vfloat4*>(x)  + (size_t)plane * (HW / 4);
    vfloat4*       op = reinterpret_cast<vfloat4*>(out)      + (size_t)plane * (HW / 4);

#pragma unroll
    for (int i = 0; i < 16; ++i) {
        vfloat4 u = xp[lane + 64 * i];
        vfloat4 v;
        v.x = fmaf(u.x, a, be);
        v.y = fmaf(u.y, a, be);
        v.z = fmaf(u.z, a, be);
        v.w = fmaf(u.w, a, be);
        __builtin_nontemporal_store(v, &op[lane + 64 * i]);
    }
}

// ---------------------------------------------------------------------------
extern "C" void kernel_launch(void* const* d_in, const int* in_sizes, int n_in,
                              void* d_out, int out_size, void* d_ws, size_t ws_size,
                              hipStream_t stream) {
    const float* x     = (const float*)d_in[0];
    const float* gamma = (const float*)d_in[1];
    const float* beta  = (const float*)d_in[2];
    float* out = (float*)d_out;

    float* sq = (float*)d_ws;                 // sq[7680] (~30 KB)

    k_sumsq<<<PLANES / 4, 256, 0, stream>>>(x, sq);
    k_apply<<<PLANES / 4, 256, 0, stream>>>(x, sq, gamma, beta, out);
}